// Round 1
// baseline (892.033 us; speedup 1.0000x reference)
//
#include <hip/hip_runtime.h>
#include <hip/hip_bf16.h>
#include <math.h>

#define T_LEN 4000
#define T4    1000
#define BDIM  256

__device__ __forceinline__ float waveReduceSum(float v) {
    #pragma unroll
    for (int off = 32; off > 0; off >>= 1) v += __shfl_down(v, off, 64);
    return v;
}

// Kernel 1: per-(b,c) row stats of x_a+x_b over T.
// stats layout [B, 4C]: [mean | std | skew | kurt]
__global__ __launch_bounds__(BDIM) void stats_kernel(
    const float* __restrict__ xa, const float* __restrict__ xb,
    float* __restrict__ stats, int C) {
    __shared__ float sdata[T_LEN];          // 16 KB: the summed row
    __shared__ float red[4];
    __shared__ float redM[12];

    const int r = blockIdx.x;               // b*C + c
    const int b = r / C;
    const int c = r - b * C;
    const int tid = threadIdx.x;
    const int wave = tid >> 6, lane = tid & 63;

    const float4* a4 = (const float4*)(xa + (size_t)r * T_LEN);
    const float4* b4 = (const float4*)(xb + (size_t)r * T_LEN);
    float4* s4 = (float4*)sdata;

    float sum = 0.f;
    for (int i = tid; i < T4; i += BDIM) {
        float4 av = a4[i], bv = b4[i];
        float4 sv = make_float4(av.x + bv.x, av.y + bv.y, av.z + bv.z, av.w + bv.w);
        s4[i] = sv;
        sum += (sv.x + sv.y) + (sv.z + sv.w);
    }
    sum = waveReduceSum(sum);
    if (lane == 0) red[wave] = sum;
    __syncthreads();                        // covers sdata writes + red writes

    const float mean = (red[0] + red[1] + red[2] + red[3]) * (1.0f / T_LEN);

    float m2 = 0.f, m3 = 0.f, m4 = 0.f;
    for (int i = tid; i < T4; i += BDIM) {
        float4 sv = s4[i];
        float dx = sv.x - mean, dy = sv.y - mean, dz = sv.z - mean, dw = sv.w - mean;
        float dx2 = dx * dx, dy2 = dy * dy, dz2 = dz * dz, dw2 = dw * dw;
        m2 += (dx2 + dy2) + (dz2 + dw2);
        m3 += (dx2 * dx + dy2 * dy) + (dz2 * dz + dw2 * dw);
        m4 += (dx2 * dx2 + dy2 * dy2) + (dz2 * dz2 + dw2 * dw2);
    }
    m2 = waveReduceSum(m2);
    m3 = waveReduceSum(m3);
    m4 = waveReduceSum(m4);
    if (lane == 0) { redM[wave] = m2; redM[4 + wave] = m3; redM[8 + wave] = m4; }
    __syncthreads();

    if (tid == 0) {
        float M2 = redM[0] + redM[1] + redM[2] + redM[3];
        float M3 = redM[4] + redM[5] + redM[6] + redM[7];
        float M4 = redM[8] + redM[9] + redM[10] + redM[11];
        float var_b = M2 / (float)(T_LEN - 1);   // unbiased
        float sd = sqrtf(var_b);
        float d = fmaxf(sd, 0.01f);
        float inv = 1.0f / d;
        float inv2 = inv * inv;
        float skew = (M3 * (1.0f / T_LEN)) * inv2 * inv;
        float kurt = (M4 * (1.0f / T_LEN)) * inv2 * inv2;
        float* srow = stats + (size_t)b * (4 * C);
        srow[c]         = mean;
        srow[C + c]     = sd;
        srow[2 * C + c] = skew;
        srow[3 * C + c] = kurt;
    }
}

// Kernel 2: h[b,o] = b1[o] + sum_j stats[b,j] * W1[o,j]   (W1: [C, 4C])
__global__ __launch_bounds__(BDIM) void h_kernel(
    const float* __restrict__ stats, const float* __restrict__ W1,
    const float* __restrict__ b1, float* __restrict__ h, int C) {
    __shared__ float sst[2048];
    const int b = blockIdx.x;
    const int tid = threadIdx.x;
    const int H = 4 * C;

    for (int i = tid; i < H; i += BDIM) sst[i] = stats[(size_t)b * H + i];
    __syncthreads();

    const float4* s4 = (const float4*)sst;
    for (int o = tid; o < C; o += BDIM) {
        const float4* w4 = (const float4*)(W1 + (size_t)o * H);
        float acc = 0.f;
        #pragma unroll 4
        for (int j = 0; j < 2048 / 4; ++j) {
            float4 w = w4[j];
            float4 s = s4[j];
            acc += (w.x * s.x + w.y * s.y) + (w.z * s.z + w.w * s.w);
        }
        h[(size_t)b * C + o] = acc + b1[o];
    }
}

// Kernel 3: gate g[b,o] = softmax_k( h[b,:]·W2[k,o,:] + b2[k,o] )[k=0]
//         = sigmoid(l0 - l1)
__global__ __launch_bounds__(BDIM) void gate_kernel(
    const float* __restrict__ h, const float* __restrict__ W2,
    const float* __restrict__ b2, float* __restrict__ g, int C) {
    __shared__ float sh[512];
    const int b = blockIdx.x;
    const int tid = threadIdx.x;

    for (int i = tid; i < C; i += BDIM) sh[i] = h[(size_t)b * C + i];
    __syncthreads();

    const float4* s4 = (const float4*)sh;
    for (int o = tid; o < C; o += BDIM) {
        const float4* w0 = (const float4*)(W2 + (size_t)o * C);
        const float4* w1 = (const float4*)(W2 + (size_t)C * C + (size_t)o * C);
        float l0 = 0.f, l1 = 0.f;
        #pragma unroll 4
        for (int j = 0; j < 512 / 4; ++j) {
            float4 s = s4[j];
            float4 a = w0[j];
            float4 bb = w1[j];
            l0 += (a.x * s.x + a.y * s.y) + (a.z * s.z + a.w * s.w);
            l1 += (bb.x * s.x + bb.y * s.y) + (bb.z * s.z + bb.w * s.w);
        }
        l0 += b2[o];
        l1 += b2[C + o];
        g[(size_t)b * C + o] = 1.0f / (1.0f + expf(l1 - l0));
    }
}

// Kernel 4: out[b,c,t] = g[b,c]*xa + (1-g[b,c])*xb
__global__ __launch_bounds__(BDIM) void mix_kernel(
    const float* __restrict__ xa, const float* __restrict__ xb,
    const float* __restrict__ g, float* __restrict__ out) {
    const int r = blockIdx.x;   // b*C + c
    const float gr = g[r];
    const float hr = 1.0f - gr;
    const float4* a4 = (const float4*)(xa + (size_t)r * T_LEN);
    const float4* b4 = (const float4*)(xb + (size_t)r * T_LEN);
    float4* o4 = (float4*)(out + (size_t)r * T_LEN);
    for (int i = threadIdx.x; i < T4; i += BDIM) {
        float4 a = a4[i], b = b4[i];
        o4[i] = make_float4(gr * a.x + hr * b.x,
                            gr * a.y + hr * b.y,
                            gr * a.z + hr * b.z,
                            gr * a.w + hr * b.w);
    }
}

extern "C" void kernel_launch(void* const* d_in, const int* in_sizes, int n_in,
                              void* d_out, int out_size, void* d_ws, size_t ws_size,
                              hipStream_t stream) {
    const float* xa = (const float*)d_in[0];   // [B, C, T]
    const float* xb = (const float*)d_in[1];   // [B, C, T]
    const float* W1 = (const float*)d_in[2];   // [C, 4C]
    const float* b1 = (const float*)d_in[3];   // [C]
    const float* W2 = (const float*)d_in[4];   // [2, C, C]
    const float* b2 = (const float*)d_in[5];   // [2, C]
    float* out = (float*)d_out;

    const int C = in_sizes[3];                 // 512
    const int B = in_sizes[0] / (C * T_LEN);   // 32

    // workspace layout
    float* stats = (float*)d_ws;                       // B * 4C
    float* h     = stats + (size_t)B * 4 * C;          // B * C
    float* g     = h + (size_t)B * C;                  // B * C

    stats_kernel<<<B * C, BDIM, 0, stream>>>(xa, xb, stats, C);
    h_kernel<<<B, BDIM, 0, stream>>>(stats, W1, b1, h, C);
    gate_kernel<<<B, BDIM, 0, stream>>>(h, W2, b2, g, C);
    mix_kernel<<<B * C, BDIM, 0, stream>>>(xa, xb, g, out);
}

// Round 2
// 677.213 us; speedup vs baseline: 1.3172x; 1.3172x over previous
//
#include <hip/hip_runtime.h>
#include <hip/hip_bf16.h>
#include <math.h>

#define T_LEN 4000
#define T4    1000
#define BDIM  256
#define EPS   0.01f

__device__ __forceinline__ float waveReduceSum(float v) {
    #pragma unroll
    for (int off = 32; off > 0; off >>= 1) v += __shfl_down(v, off, 64);
    return v;
}

// Kernel 1: per-(b,c) row stats of x_a+x_b over T, single streaming pass.
// Raw power sums S1..S4 -> central moments algebraically.
// stats layout [B, 4C]: [mean | std | skew | kurt]
__global__ __launch_bounds__(BDIM) void stats_kernel(
    const float* __restrict__ xa, const float* __restrict__ xb,
    float* __restrict__ stats, int C) {
    __shared__ float red[4][4];             // [wave][S1..S4]

    const int r = blockIdx.x;               // b*C + c
    const int b = r / C;
    const int c = r - b * C;
    const int tid = threadIdx.x;
    const int wave = tid >> 6, lane = tid & 63;

    const float4* a4 = (const float4*)(xa + (size_t)r * T_LEN);
    const float4* b4 = (const float4*)(xb + (size_t)r * T_LEN);

    float s1 = 0.f, s2 = 0.f, s3 = 0.f, s4 = 0.f;
    for (int i = tid; i < T4; i += BDIM) {
        float4 av = a4[i], bv = b4[i];
        float x0 = av.x + bv.x, x1 = av.y + bv.y, x2 = av.z + bv.z, x3 = av.w + bv.w;
        float q0 = x0 * x0, q1 = x1 * x1, q2 = x2 * x2, q3 = x3 * x3;
        s1 += (x0 + x1) + (x2 + x3);
        s2 += (q0 + q1) + (q2 + q3);
        s3 += (q0 * x0 + q1 * x1) + (q2 * x2 + q3 * x3);
        s4 += (q0 * q0 + q1 * q1) + (q2 * q2 + q3 * q3);
    }
    s1 = waveReduceSum(s1);
    s2 = waveReduceSum(s2);
    s3 = waveReduceSum(s3);
    s4 = waveReduceSum(s4);
    if (lane == 0) { red[wave][0] = s1; red[wave][1] = s2; red[wave][2] = s3; red[wave][3] = s4; }
    __syncthreads();

    if (tid == 0) {
        float S1 = red[0][0] + red[1][0] + red[2][0] + red[3][0];
        float S2 = red[0][1] + red[1][1] + red[2][1] + red[3][1];
        float S3 = red[0][2] + red[1][2] + red[2][2] + red[3][2];
        float S4 = red[0][3] + red[1][3] + red[2][3] + red[3][3];
        const float invT = 1.0f / T_LEN;
        float mean = S1 * invT;
        float m = mean, m2c = m * m;
        // central sums: T*mean^k = mean^{k-1}*S1
        float M2 = S2 - S1 * m;
        float M3 = S3 - 3.0f * m * S2 + 2.0f * m2c * S1;
        float M4 = S4 - 4.0f * m * S3 + 6.0f * m2c * S2 - 3.0f * m2c * m * S1;
        float var_b = M2 / (float)(T_LEN - 1);
        float sd = sqrtf(fmaxf(var_b, 0.0f));
        float d = fmaxf(sd, EPS);
        float inv = 1.0f / d;
        float inv2 = inv * inv;
        float skew = (M3 * invT) * inv2 * inv;
        float kurt = (M4 * invT) * inv2 * inv2;
        float* srow = stats + (size_t)b * (4 * C);
        srow[c]         = mean;
        srow[C + c]     = sd;
        srow[2 * C + c] = skew;
        srow[3 * C + c] = kurt;
    }
}

// Kernel 2: h[b,o] = b1[o] + sum_j stats[b,j] * W1[o,j]   (W1: [C, 4C])
// One wave per output o; grid = B * C/4, block = 4 waves.
__global__ __launch_bounds__(BDIM) void h_kernel(
    const float* __restrict__ stats, const float* __restrict__ W1,
    const float* __restrict__ b1, float* __restrict__ h, int C) {
    __shared__ float sst[2048];             // stats row, 8 KB
    const int H = 4 * C;
    const int groups = C / 4;               // outputs per batch / waves per block
    const int b = blockIdx.x / groups;
    const int grp = blockIdx.x - b * groups;
    const int tid = threadIdx.x;
    const int wave = tid >> 6, lane = tid & 63;
    const int o = grp * 4 + wave;

    for (int i = tid; i < H; i += BDIM) sst[i] = stats[(size_t)b * H + i];
    __syncthreads();

    const float4* s4 = (const float4*)sst;
    const float4* w4 = (const float4*)(W1 + (size_t)o * H);
    float acc = 0.f;
    const int n4 = H / 4;                   // 512 float4
    #pragma unroll
    for (int it = 0; it < 8; ++it) {
        int idx = it * 64 + lane;
        if (idx < n4) {
            float4 w = w4[idx];
            float4 s = s4[idx];
            acc += (w.x * s.x + w.y * s.y) + (w.z * s.z + w.w * s.w);
        }
    }
    acc = waveReduceSum(acc);
    if (lane == 0) h[(size_t)b * C + o] = acc + b1[o];
}

// Kernel 3: fused gate + blend. One block per (b,c) row.
// gate = softmax over 2 branches = sigmoid(l0 - l1), then
// out[b,c,:] = g*xa + (1-g)*xb
__global__ __launch_bounds__(BDIM) void mixgate_kernel(
    const float* __restrict__ xa, const float* __restrict__ xb,
    const float* __restrict__ h, const float* __restrict__ W2,
    const float* __restrict__ b2, float* __restrict__ out, int C) {
    __shared__ float red0[4], red1[4];
    __shared__ float sg;

    const int r = blockIdx.x;               // b*C + c
    const int b = r / C;
    const int c = r - b * C;
    const int tid = threadIdx.x;
    const int wave = tid >> 6, lane = tid & 63;

    // --- gate: l_k = h[b,:] . W2[k,c,:] + b2[k,c]
    const float2* h2 = (const float2*)(h + (size_t)b * C);
    const float2* w0 = (const float2*)(W2 + (size_t)c * C);
    const float2* w1 = (const float2*)(W2 + (size_t)C * C + (size_t)c * C);
    float l0 = 0.f, l1 = 0.f;
    for (int i = tid; i < C / 2; i += BDIM) {
        float2 hv = h2[i];
        float2 a0 = w0[i];
        float2 a1 = w1[i];
        l0 += hv.x * a0.x + hv.y * a0.y;
        l1 += hv.x * a1.x + hv.y * a1.y;
    }
    l0 = waveReduceSum(l0);
    l1 = waveReduceSum(l1);
    if (lane == 0) { red0[wave] = l0; red1[wave] = l1; }
    __syncthreads();
    if (tid == 0) {
        float L0 = (red0[0] + red0[1]) + (red0[2] + red0[3]) + b2[c];
        float L1 = (red1[0] + red1[1]) + (red1[2] + red1[3]) + b2[C + c];
        sg = 1.0f / (1.0f + expf(L1 - L0));
    }
    __syncthreads();

    const float g = sg;
    const float hg = 1.0f - g;

    // --- blend
    const float4* a4 = (const float4*)(xa + (size_t)r * T_LEN);
    const float4* b4 = (const float4*)(xb + (size_t)r * T_LEN);
    float4* o4 = (float4*)(out + (size_t)r * T_LEN);
    for (int i = tid; i < T4; i += BDIM) {
        float4 a = a4[i], bb = b4[i];
        o4[i] = make_float4(g * a.x + hg * bb.x,
                            g * a.y + hg * bb.y,
                            g * a.z + hg * bb.z,
                            g * a.w + hg * bb.w);
    }
}

extern "C" void kernel_launch(void* const* d_in, const int* in_sizes, int n_in,
                              void* d_out, int out_size, void* d_ws, size_t ws_size,
                              hipStream_t stream) {
    const float* xa = (const float*)d_in[0];   // [B, C, T]
    const float* xb = (const float*)d_in[1];   // [B, C, T]
    const float* W1 = (const float*)d_in[2];   // [C, 4C]
    const float* b1 = (const float*)d_in[3];   // [C]
    const float* W2 = (const float*)d_in[4];   // [2, C, C]
    const float* b2 = (const float*)d_in[5];   // [2, C]
    float* out = (float*)d_out;

    const int C = in_sizes[3];                 // 512
    const int B = in_sizes[0] / (C * T_LEN);   // 32

    // workspace layout
    float* stats = (float*)d_ws;                       // B * 4C
    float* h     = stats + (size_t)B * 4 * C;          // B * C

    stats_kernel<<<B * C, BDIM, 0, stream>>>(xa, xb, stats, C);
    h_kernel<<<B * (C / 4), BDIM, 0, stream>>>(stats, W1, b1, h, C);
    mixgate_kernel<<<B * C, BDIM, 0, stream>>>(xa, xb, h, W2, b2, out, C);
}